// Round 5
// baseline (998.382 us; speedup 1.0000x reference)
//
#include <hip/hip_runtime.h>
#include <math.h>

#define NEG_INF_KEY 0x807fffff  // fkey(-INFINITY)

__device__ __forceinline__ float elu1(float v) {
    return v > 0.f ? v : __expf(v) - 1.f;
}
__device__ __forceinline__ int fkey(float x) {
    int b = __float_as_int(x);
    return b >= 0 ? b : (b ^ 0x7fffffff);
}
__device__ __forceinline__ float finv(int k) {
    return __int_as_float(k >= 0 ? k : (k ^ 0x7fffffff));
}

// ---------------------------------------------------------------- init ----
__global__ __launch_bounds__(256) void k_init(float* __restrict__ out, int out_n,
                                              int* __restrict__ keys, int nk) {
    int i = blockIdx.x * blockDim.x + threadIdx.x;
    int stride = gridDim.x * blockDim.x;
    for (int j = i; j < out_n; j += stride) out[j] = 0.f;
    for (int j = i; j < nk; j += stride) keys[j] = NEG_INF_KEY;
}

// ------------------------------------------------------- h = x @ W + b ----
// block: 256 threads = 2 halves x 128 dims; 8 nodes per block-iteration.
__global__ __launch_bounds__(256) void k_h(const float* __restrict__ x,
                                           const float* __restrict__ W,
                                           const float* __restrict__ b,
                                           float* __restrict__ h, int N) {
    __shared__ float  Wl[63 * 128];
    __shared__ float4 xq[2][64];   // xq[half][k] = x[k] for 4 consecutive nodes

    int t = threadIdx.x;
    for (int i = t; i < 63 * 128; i += 256) Wl[i] = W[i];
    int d    = t & 127;
    int half = t >> 7;
    float bd = b[d];

    for (int base = blockIdx.x * 8; base < N; base += gridDim.x * 8) {
        int n0 = base + half * 4;
        __syncthreads();
        // cooperative load of 8 x-rows (8*63 = 504 elements)
        for (int i = t; i < 504; i += 256) {
            int k = i >> 3, j = i & 7;
            int n = base + j;
            ((float*)&xq[j >> 2][k])[j & 3] = (n < N) ? x[n * 63 + k] : 0.f;
        }
        __syncthreads();
        float a0 = bd, a1 = bd, a2 = bd, a3 = bd;
#pragma unroll
        for (int k = 0; k < 63; ++k) {
            float  w  = Wl[k * 128 + d];
            float4 xv = xq[half][k];
            a0 = fmaf(xv.x, w, a0);
            a1 = fmaf(xv.y, w, a1);
            a2 = fmaf(xv.z, w, a2);
            a3 = fmaf(xv.w, w, a3);
        }
        if (n0 + 0 < N) h[(n0 + 0) * 128 + d] = a0;
        if (n0 + 1 < N) h[(n0 + 1) * 128 + d] = a1;
        if (n0 + 2 < N) h[(n0 + 2) * 128 + d] = a2;
        if (n0 + 3 < N) h[(n0 + 3) * 128 + d] = a3;
    }
}

// ------------------------------------------------------------ edge ------
// one wave (64 lanes) per edge; each lane owns dims (2*lane, 2*lane+1)
__global__ __launch_bounds__(256) void k_edge(
    const float* __restrict__ h, const float* __restrict__ pos,
    const float* __restrict__ attn, const float* __restrict__ W_rbf,
    const float* __restrict__ W_read, const float* __restrict__ b_read,
    const int* __restrict__ edges, const int* __restrict__ batch,
    float* __restrict__ out, int* __restrict__ keys, int E) {

    int lane = threadIdx.x & 63;
    int e    = (blockIdx.x * 256 + threadIdx.x) >> 6;
    if (e >= E) return;

    int src = edges[2 * e];
    int dst = edges[2 * e + 1];

    // distance + 6 gaussian rbf values (offsets = 0..5, coeff = -0.5)
    float dx = pos[dst * 3 + 0] - pos[src * 3 + 0];
    float dy = pos[dst * 3 + 1] - pos[src * 3 + 1];
    float dz = pos[dst * 3 + 2] - pos[src * 3 + 2];
    float dist = fmaxf(sqrtf(dx * dx + dy * dy + dz * dz), 0.1f);
    float r0 = __expf(-0.5f * (dist - 0.f) * (dist - 0.f));
    float r1 = __expf(-0.5f * (dist - 1.f) * (dist - 1.f));
    float r2 = __expf(-0.5f * (dist - 2.f) * (dist - 2.f));
    float r3 = __expf(-0.5f * (dist - 3.f) * (dist - 3.f));
    float r4 = __expf(-0.5f * (dist - 4.f) * (dist - 4.f));
    float r5 = __expf(-0.5f * (dist - 5.f) * (dist - 5.f));

    const float2* h2s = (const float2*)(h + (size_t)src * 128);
    const float2* h2d = (const float2*)(h + (size_t)dst * 128);
    float2 hs = h2s[lane];
    float2 hd = h2d[lane];
    float hex = elu1(hs.x + hd.x);
    float hey = elu1(hs.y + hd.y);

    const float2* Wr = (const float2*)W_rbf;
    float2 w0 = Wr[0 * 64 + lane];
    float2 w1 = Wr[1 * 64 + lane];
    float2 w2 = Wr[2 * 64 + lane];
    float2 w3 = Wr[3 * 64 + lane];
    float2 w4 = Wr[4 * 64 + lane];
    float2 w5 = Wr[5 * 64 + lane];
    float gx = r0 * w0.x + r1 * w1.x + r2 * w2.x + r3 * w3.x + r4 * w4.x + r5 * w5.x;
    float gy = r0 * w0.y + r1 * w1.y + r2 * w2.y + r3 * w3.y + r4 * w4.y + r5 * w5.y;

    float2 at = ((const float2*)attn)[lane];
    float ax = elu1(hex * gx * at.x);
    float ay = elu1(hey * gy * at.y);

    // score = sigmoid(atom . W_read + b_read)
    float2 wr = ((const float2*)W_read)[lane];
    float p = ax * wr.x + ay * wr.y;
#pragma unroll
    for (int off = 32; off; off >>= 1) p += __shfl_xor(p, off);
    float score = 1.f / (1.f + __expf(-(p + b_read[0])));

    int eb = batch[src];
    float* os = out + eb * 256 + lane * 2;
    unsafeAtomicAdd(os + 0, ax * score);
    unsafeAtomicAdd(os + 1, ay * score);
    int* km = keys + eb * 128 + lane * 2;
    atomicMax(km + 0, fkey(ax));
    atomicMax(km + 1, fkey(ay));
}

// --------------------------------------------------------- finalize -----
__global__ __launch_bounds__(256) void k_fin(const int* __restrict__ keys,
                                             float* __restrict__ out, int n) {
    int i = blockIdx.x * blockDim.x + threadIdx.x;
    if (i >= n) return;
    int k  = keys[i];
    float v = (k == NEG_INF_KEY) ? 0.f : finv(k);
    int g = i >> 7, d = i & 127;
    out[g * 256 + 128 + d] = v;
}

// ---------------------------------------------------------------- host ---
extern "C" void kernel_launch(void* const* d_in, const int* in_sizes, int n_in,
                              void* d_out, int out_size, void* d_ws, size_t ws_size,
                              hipStream_t stream) {
    const float* x      = (const float*)d_in[0];
    const float* pos    = (const float*)d_in[1];
    const float* W      = (const float*)d_in[2];
    const float* b      = (const float*)d_in[3];
    const float* attn   = (const float*)d_in[4];
    const float* W_rbf  = (const float*)d_in[5];
    const float* W_read = (const float*)d_in[6];
    const float* b_read = (const float*)d_in[7];
    const int*   edges  = (const int*)d_in[8];
    const int*   batch  = (const int*)d_in[9];
    float* out = (float*)d_out;

    const int N = 200000, E = 400000, G = 4096;

    float* h    = (float*)d_ws;                                   // N*128 f32 = 102.4 MB
    int*   keys = (int*)((char*)d_ws + (size_t)N * 128 * 4);      // G*128 i32 = 2 MB

    k_init<<<2048, 256, 0, stream>>>(out, G * 256, keys, G * 128);
    k_h<<<4096, 256, 0, stream>>>(x, W, b, h, N);
    k_edge<<<(E * 64 + 255) / 256, 256, 0, stream>>>(h, pos, attn, W_rbf, W_read,
                                                     b_read, edges, batch, out, keys, E);
    k_fin<<<(G * 128 + 255) / 256, 256, 0, stream>>>(keys, out, G * 128);
}

// Round 7
// 598.098 us; speedup vs baseline: 1.6693x; 1.6693x over previous
//
#include <hip/hip_runtime.h>
#include <math.h>

constexpr int Nn = 200000, Ee = 400000, Gg = 4096;

__device__ __forceinline__ float elu1(float v) {
    return v > 0.f ? v : __expf(v) - 1.f;
}

// ----------------------------------------------------------- zero hist ----
__global__ __launch_bounds__(256) void k_zero(int* __restrict__ hist) {
    int i = blockIdx.x * 256 + threadIdx.x;
    if (i < Gg) hist[i] = 0;
}

// ------------------------------------------- histogram + eb cache ---------
__global__ __launch_bounds__(256) void k_hist(const int* __restrict__ edges,
                                              const int* __restrict__ batch,
                                              int* __restrict__ hist,
                                              int* __restrict__ ebuf) {
    int e = blockIdx.x * 256 + threadIdx.x;
    if (e >= Ee) return;
    int eb = batch[edges[2 * e]];
    ebuf[e] = eb;
    atomicAdd(&hist[eb], 1);
}

// ------------------- exclusive scan (1 block, 256 thr, 16 bins/thread) ----
__global__ __launch_bounds__(256) void k_scan(const int* __restrict__ hist,
                                              int* __restrict__ offsets,
                                              int* __restrict__ cursor) {
    __shared__ int part[256];
    int t = threadIdx.x;
    int local[16];
    int s = 0;
#pragma unroll
    for (int j = 0; j < 16; ++j) { local[j] = s; s += hist[t * 16 + j]; }
    part[t] = s;
    __syncthreads();
    for (int off = 1; off < 256; off <<= 1) {
        int v = (t >= off) ? part[t - off] : 0;
        __syncthreads();
        part[t] += v;
        __syncthreads();
    }
    int pre = (t == 0) ? 0 : part[t - 1];
#pragma unroll
    for (int j = 0; j < 16; ++j) {
        int o = pre + local[j];
        offsets[t * 16 + j] = o;
        cursor[t * 16 + j]  = o;
    }
}

// ------------------------------------------------------------ scatter -----
__global__ __launch_bounds__(256) void k_scatter(const int* __restrict__ ebuf,
                                                 int* __restrict__ cursor,
                                                 int* __restrict__ order) {
    int e = blockIdx.x * 256 + threadIdx.x;
    if (e >= Ee) return;
    int p = atomicAdd(&cursor[ebuf[e]], 1);
    order[p] = e;
}

// ------------------------------------------------------- h = x @ W + b ----
__global__ __launch_bounds__(256) void k_h(const float* __restrict__ x,
                                           const float* __restrict__ W,
                                           const float* __restrict__ b,
                                           float* __restrict__ h, int N) {
    __shared__ float  Wl[63 * 128];
    __shared__ float4 xq[2][64];

    int t = threadIdx.x;
    for (int i = t; i < 63 * 128; i += 256) Wl[i] = W[i];
    int d    = t & 127;
    int half = t >> 7;
    float bd = b[d];

    for (int base = blockIdx.x * 8; base < N; base += gridDim.x * 8) {
        int n0 = base + half * 4;
        __syncthreads();
        for (int i = t; i < 504; i += 256) {
            int k = i >> 3, j = i & 7;
            int n = base + j;
            ((float*)&xq[j >> 2][k])[j & 3] = (n < N) ? x[n * 63 + k] : 0.f;
        }
        __syncthreads();
        float a0 = bd, a1 = bd, a2 = bd, a3 = bd;
#pragma unroll
        for (int k = 0; k < 63; ++k) {
            float  w  = Wl[k * 128 + d];
            float4 xv = xq[half][k];
            a0 = fmaf(xv.x, w, a0);
            a1 = fmaf(xv.y, w, a1);
            a2 = fmaf(xv.z, w, a2);
            a3 = fmaf(xv.w, w, a3);
        }
        if (n0 + 0 < N) h[(n0 + 0) * 128 + d] = a0;
        if (n0 + 1 < N) h[(n0 + 1) * 128 + d] = a1;
        if (n0 + 2 < N) h[(n0 + 2) * 128 + d] = a2;
        if (n0 + 3 < N) h[(n0 + 3) * 128 + d] = a3;
    }
}

// --------------------------- per-segment reduction (no float atomics) -----
// one block per segment; 4 waves round-robin over the segment's edges;
// lane owns dims (2*lane, 2*lane+1); register accumulate, LDS combine.
__global__ __launch_bounds__(256) void k_reduce(
    const float* __restrict__ h, const float* __restrict__ pos,
    const float* __restrict__ attn, const float* __restrict__ W_rbf,
    const float* __restrict__ W_read, const float* __restrict__ b_read,
    const int* __restrict__ edges, const int* __restrict__ order,
    const int* __restrict__ offsets, const int* __restrict__ hist,
    float* __restrict__ out) {

    __shared__ float lsum[4][256];
    __shared__ float lmax[4][256];

    int g    = blockIdx.x;
    int t    = threadIdx.x;
    int lane = t & 63;
    int wv   = t >> 6;
    int start = offsets[g];
    int cnt   = hist[g];

    const float2* Wr = (const float2*)W_rbf;
    float2 w0 = Wr[0 * 64 + lane];
    float2 w1 = Wr[1 * 64 + lane];
    float2 w2 = Wr[2 * 64 + lane];
    float2 w3 = Wr[3 * 64 + lane];
    float2 w4 = Wr[4 * 64 + lane];
    float2 w5 = Wr[5 * 64 + lane];
    float2 at = ((const float2*)attn)[lane];
    float2 wr = ((const float2*)W_read)[lane];
    float  br = b_read[0];

    float sx = 0.f, sy = 0.f;
    float mx = -INFINITY, my = -INFINITY;

    for (int i = wv; i < cnt; i += 4) {
        int e   = order[start + i];
        int src = edges[2 * e];
        int dst = edges[2 * e + 1];

        float dx = pos[dst * 3 + 0] - pos[src * 3 + 0];
        float dy = pos[dst * 3 + 1] - pos[src * 3 + 1];
        float dz = pos[dst * 3 + 2] - pos[src * 3 + 2];
        float dist = fmaxf(sqrtf(dx * dx + dy * dy + dz * dz), 0.1f);
        float r0 = __expf(-0.5f * (dist - 0.f) * (dist - 0.f));
        float r1 = __expf(-0.5f * (dist - 1.f) * (dist - 1.f));
        float r2 = __expf(-0.5f * (dist - 2.f) * (dist - 2.f));
        float r3 = __expf(-0.5f * (dist - 3.f) * (dist - 3.f));
        float r4 = __expf(-0.5f * (dist - 4.f) * (dist - 4.f));
        float r5 = __expf(-0.5f * (dist - 5.f) * (dist - 5.f));

        float2 hs = ((const float2*)(h + (size_t)src * 128))[lane];
        float2 hd = ((const float2*)(h + (size_t)dst * 128))[lane];
        float hex = elu1(hs.x + hd.x);
        float hey = elu1(hs.y + hd.y);

        float gx = r0 * w0.x + r1 * w1.x + r2 * w2.x + r3 * w3.x + r4 * w4.x + r5 * w5.x;
        float gy = r0 * w0.y + r1 * w1.y + r2 * w2.y + r3 * w3.y + r4 * w4.y + r5 * w5.y;

        float ax = elu1(hex * gx * at.x);
        float ay = elu1(hey * gy * at.y);

        float p = ax * wr.x + ay * wr.y;
#pragma unroll
        for (int off = 32; off; off >>= 1) p += __shfl_xor(p, off);
        float score = 1.f / (1.f + __expf(-(p + br)));

        sx = fmaf(ax, score, sx);
        sy = fmaf(ay, score, sy);
        mx = fmaxf(mx, ax);
        my = fmaxf(my, ay);
    }

    lsum[wv][lane * 2 + 0] = sx;
    lsum[wv][lane * 2 + 1] = sy;
    lmax[wv][lane * 2 + 0] = mx;
    lmax[wv][lane * 2 + 1] = my;
    __syncthreads();

    float r;
    if (t < 128) {
        r = lsum[0][t] + lsum[1][t] + lsum[2][t] + lsum[3][t];
    } else {
        int d = t - 128;
        float m = fmaxf(fmaxf(lmax[0][d], lmax[1][d]),
                        fmaxf(lmax[2][d], lmax[3][d]));
        r = (m > -3.0e38f) ? m : 0.f;   // empty segment -> 0 (isfinite fixup)
    }
    out[g * 256 + t] = r;
}

// ---------------------------------------------------------------- host ---
extern "C" void kernel_launch(void* const* d_in, const int* in_sizes, int n_in,
                              void* d_out, int out_size, void* d_ws, size_t ws_size,
                              hipStream_t stream) {
    const float* x      = (const float*)d_in[0];
    const float* pos    = (const float*)d_in[1];
    const float* W      = (const float*)d_in[2];
    const float* b      = (const float*)d_in[3];
    const float* attn   = (const float*)d_in[4];
    const float* W_rbf  = (const float*)d_in[5];
    const float* W_read = (const float*)d_in[6];
    const float* b_read = (const float*)d_in[7];
    const int*   edges  = (const int*)d_in[8];
    const int*   batch  = (const int*)d_in[9];
    float* out = (float*)d_out;

    char* p = (char*)d_ws;
    float* h       = (float*)p;                 p += (size_t)Nn * 128 * 4;  // 102.4 MB
    int*   hist    = (int*)p;                   p += Gg * 4;
    int*   offsets = (int*)p;                   p += Gg * 4;
    int*   cursor  = (int*)p;                   p += Gg * 4;
    int*   ebuf    = (int*)p;                   p += Ee * 4;
    int*   order   = (int*)p;                   p += Ee * 4;

    k_zero<<<(Gg + 255) / 256, 256, 0, stream>>>(hist);
    k_hist<<<(Ee + 255) / 256, 256, 0, stream>>>(edges, batch, hist, ebuf);
    k_scan<<<1, 256, 0, stream>>>(hist, offsets, cursor);
    k_scatter<<<(Ee + 255) / 256, 256, 0, stream>>>(ebuf, cursor, order);
    k_h<<<4096, 256, 0, stream>>>(x, W, b, h, Nn);
    k_reduce<<<Gg, 256, 0, stream>>>(h, pos, attn, W_rbf, W_read, b_read,
                                     edges, order, offsets, hist, out);
}

// Round 9
// 508.674 us; speedup vs baseline: 1.9627x; 1.1758x over previous
//
#include <hip/hip_runtime.h>
#include <math.h>

constexpr int Nn = 200000, Ee = 400000, Gg = 4096;

__device__ __forceinline__ float elu1(float v) {
    return v > 0.f ? v : __expf(v) - 1.f;
}

// ----------------------------------------------------------- zero hist ----
__global__ __launch_bounds__(256) void k_zero(int* __restrict__ hist) {
    int i = blockIdx.x * 256 + threadIdx.x;
    if (i < Gg) hist[i] = 0;
}

// ------------------------------------------- histogram + eb cache ---------
__global__ __launch_bounds__(256) void k_hist(const int* __restrict__ edges,
                                              const int* __restrict__ batch,
                                              int* __restrict__ hist,
                                              int* __restrict__ ebuf) {
    int e = blockIdx.x * 256 + threadIdx.x;
    if (e >= Ee) return;
    int eb = batch[edges[2 * e]];
    ebuf[e] = eb;
    atomicAdd(&hist[eb], 1);
}

// ------------------- exclusive scan (1 block, 256 thr, 16 bins/thread) ----
__global__ __launch_bounds__(256) void k_scan(const int* __restrict__ hist,
                                              int* __restrict__ offsets,
                                              int* __restrict__ cursor) {
    __shared__ int part[256];
    int t = threadIdx.x;
    int local[16];
    int s = 0;
#pragma unroll
    for (int j = 0; j < 16; ++j) { local[j] = s; s += hist[t * 16 + j]; }
    part[t] = s;
    __syncthreads();
    for (int off = 1; off < 256; off <<= 1) {
        int v = (t >= off) ? part[t - off] : 0;
        __syncthreads();
        part[t] += v;
        __syncthreads();
    }
    int pre = (t == 0) ? 0 : part[t - 1];
#pragma unroll
    for (int j = 0; j < 16; ++j) {
        int o = pre + local[j];
        offsets[t * 16 + j] = o;
        cursor[t * 16 + j]  = o;
    }
}

// ------------------------------------------------------------ scatter -----
__global__ __launch_bounds__(256) void k_scatter(const int* __restrict__ ebuf,
                                                 int* __restrict__ cursor,
                                                 int* __restrict__ order) {
    int e = blockIdx.x * 256 + threadIdx.x;
    if (e >= Ee) return;
    int p = atomicAdd(&cursor[ebuf[e]], 1);
    order[p] = e;
}

// --------------------------------- pad x (N x 63) -> x64 (N x 64, 16B rows)
__global__ __launch_bounds__(256) void k_pad(const float* __restrict__ x,
                                             float* __restrict__ x64) {
    int total = Nn * 64;
    for (int i = blockIdx.x * 256 + threadIdx.x; i < total; i += gridDim.x * 256) {
        int n = i >> 6, k = i & 63;
        x64[i] = (k < 63) ? x[n * 63 + k] : 0.f;
    }
}

// ------------------------------------------------------- h = x @ W + b ----
// No LDS. Thread owns dim d = t&127; W column in registers; x rows read as
// uniform-address float4 (L1 broadcast). 8 nodes/block-iter (4 per half),
// 4 independent FMA chains per thread. 200000 % 8 == 0 -> no tail guards.
__global__ __launch_bounds__(256) void k_h(const float* __restrict__ x64,
                                           const float* __restrict__ W,
                                           const float* __restrict__ b,
                                           float* __restrict__ h, int N) {
    int t    = threadIdx.x;
    int d    = t & 127;
    int half = t >> 7;

    float w[64];
#pragma unroll
    for (int k = 0; k < 63; ++k) w[k] = W[k * 128 + d];
    w[63] = 0.f;
    float bd = b[d];

    for (int base = blockIdx.x * 8; base < N; base += gridDim.x * 8) {
        int n0 = base + half * 4;
        const float4* r0 = (const float4*)(x64 + (size_t)(n0 + 0) * 64);
        const float4* r1 = (const float4*)(x64 + (size_t)(n0 + 1) * 64);
        const float4* r2 = (const float4*)(x64 + (size_t)(n0 + 2) * 64);
        const float4* r3 = (const float4*)(x64 + (size_t)(n0 + 3) * 64);
        float a0 = bd, a1 = bd, a2 = bd, a3 = bd;
#pragma unroll
        for (int c = 0; c < 16; ++c) {
            float4 v0 = r0[c], v1 = r1[c], v2 = r2[c], v3 = r3[c];
            a0 = fmaf(v0.x, w[4 * c + 0], a0);
            a0 = fmaf(v0.y, w[4 * c + 1], a0);
            a0 = fmaf(v0.z, w[4 * c + 2], a0);
            a0 = fmaf(v0.w, w[4 * c + 3], a0);
            a1 = fmaf(v1.x, w[4 * c + 0], a1);
            a1 = fmaf(v1.y, w[4 * c + 1], a1);
            a1 = fmaf(v1.z, w[4 * c + 2], a1);
            a1 = fmaf(v1.w, w[4 * c + 3], a1);
            a2 = fmaf(v2.x, w[4 * c + 0], a2);
            a2 = fmaf(v2.y, w[4 * c + 1], a2);
            a2 = fmaf(v2.z, w[4 * c + 2], a2);
            a2 = fmaf(v2.w, w[4 * c + 3], a2);
            a3 = fmaf(v3.x, w[4 * c + 0], a3);
            a3 = fmaf(v3.y, w[4 * c + 1], a3);
            a3 = fmaf(v3.z, w[4 * c + 2], a3);
            a3 = fmaf(v3.w, w[4 * c + 3], a3);
        }
        h[(size_t)(n0 + 0) * 128 + d] = a0;
        h[(size_t)(n0 + 1) * 128 + d] = a1;
        h[(size_t)(n0 + 2) * 128 + d] = a2;
        h[(size_t)(n0 + 3) * 128 + d] = a3;
    }
}

// --------------------------- per-segment reduction (no float atomics) -----
__global__ __launch_bounds__(256) void k_reduce(
    const float* __restrict__ h, const float* __restrict__ pos,
    const float* __restrict__ attn, const float* __restrict__ W_rbf,
    const float* __restrict__ W_read, const float* __restrict__ b_read,
    const int* __restrict__ edges, const int* __restrict__ order,
    const int* __restrict__ offsets, const int* __restrict__ hist,
    float* __restrict__ out) {

    __shared__ float lsum[4][256];
    __shared__ float lmax[4][256];

    int g    = blockIdx.x;
    int t    = threadIdx.x;
    int lane = t & 63;
    int wv   = t >> 6;
    int start = offsets[g];
    int cnt   = hist[g];

    const float2* Wr = (const float2*)W_rbf;
    float2 w0 = Wr[0 * 64 + lane];
    float2 w1 = Wr[1 * 64 + lane];
    float2 w2 = Wr[2 * 64 + lane];
    float2 w3 = Wr[3 * 64 + lane];
    float2 w4 = Wr[4 * 64 + lane];
    float2 w5 = Wr[5 * 64 + lane];
    float2 at = ((const float2*)attn)[lane];
    float2 wr = ((const float2*)W_read)[lane];
    float  br = b_read[0];

    float sx = 0.f, sy = 0.f;
    float mx = -INFINITY, my = -INFINITY;

    for (int i = wv; i < cnt; i += 4) {
        int e   = order[start + i];
        int src = edges[2 * e];
        int dst = edges[2 * e + 1];

        float dx = pos[dst * 3 + 0] - pos[src * 3 + 0];
        float dy = pos[dst * 3 + 1] - pos[src * 3 + 1];
        float dz = pos[dst * 3 + 2] - pos[src * 3 + 2];
        float dist = fmaxf(sqrtf(dx * dx + dy * dy + dz * dz), 0.1f);
        float r0 = __expf(-0.5f * (dist - 0.f) * (dist - 0.f));
        float r1 = __expf(-0.5f * (dist - 1.f) * (dist - 1.f));
        float r2 = __expf(-0.5f * (dist - 2.f) * (dist - 2.f));
        float r3 = __expf(-0.5f * (dist - 3.f) * (dist - 3.f));
        float r4 = __expf(-0.5f * (dist - 4.f) * (dist - 4.f));
        float r5 = __expf(-0.5f * (dist - 5.f) * (dist - 5.f));

        float2 hs = ((const float2*)(h + (size_t)src * 128))[lane];
        float2 hd = ((const float2*)(h + (size_t)dst * 128))[lane];
        float hex = elu1(hs.x + hd.x);
        float hey = elu1(hs.y + hd.y);

        float gx = r0 * w0.x + r1 * w1.x + r2 * w2.x + r3 * w3.x + r4 * w4.x + r5 * w5.x;
        float gy = r0 * w0.y + r1 * w1.y + r2 * w2.y + r3 * w3.y + r4 * w4.y + r5 * w5.y;

        float ax = elu1(hex * gx * at.x);
        float ay = elu1(hey * gy * at.y);

        float p = ax * wr.x + ay * wr.y;
#pragma unroll
        for (int off = 32; off; off >>= 1) p += __shfl_xor(p, off);
        float score = 1.f / (1.f + __expf(-(p + br)));

        sx = fmaf(ax, score, sx);
        sy = fmaf(ay, score, sy);
        mx = fmaxf(mx, ax);
        my = fmaxf(my, ay);
    }

    lsum[wv][lane * 2 + 0] = sx;
    lsum[wv][lane * 2 + 1] = sy;
    lmax[wv][lane * 2 + 0] = mx;
    lmax[wv][lane * 2 + 1] = my;
    __syncthreads();

    float r;
    if (t < 128) {
        r = lsum[0][t] + lsum[1][t] + lsum[2][t] + lsum[3][t];
    } else {
        int d = t - 128;
        float m = fmaxf(fmaxf(lmax[0][d], lmax[1][d]),
                        fmaxf(lmax[2][d], lmax[3][d]));
        r = (m > -3.0e38f) ? m : 0.f;   // empty segment -> 0 (isfinite fixup)
    }
    out[g * 256 + t] = r;
}

// ---------------------------------------------------------------- host ---
extern "C" void kernel_launch(void* const* d_in, const int* in_sizes, int n_in,
                              void* d_out, int out_size, void* d_ws, size_t ws_size,
                              hipStream_t stream) {
    const float* x      = (const float*)d_in[0];
    const float* pos    = (const float*)d_in[1];
    const float* W      = (const float*)d_in[2];
    const float* b      = (const float*)d_in[3];
    const float* attn   = (const float*)d_in[4];
    const float* W_rbf  = (const float*)d_in[5];
    const float* W_read = (const float*)d_in[6];
    const float* b_read = (const float*)d_in[7];
    const int*   edges  = (const int*)d_in[8];
    const int*   batch  = (const int*)d_in[9];
    float* out = (float*)d_out;

    char* p = (char*)d_ws;
    float* h       = (float*)p;                 p += (size_t)Nn * 128 * 4;  // 102.4 MB
    float* x64     = (float*)p;                 p += (size_t)Nn * 64 * 4;   //  51.2 MB
    int*   hist    = (int*)p;                   p += Gg * 4;
    int*   offsets = (int*)p;                   p += Gg * 4;
    int*   cursor  = (int*)p;                   p += Gg * 4;
    int*   ebuf    = (int*)p;                   p += Ee * 4;
    int*   order   = (int*)p;                   p += Ee * 4;

    k_zero<<<(Gg + 255) / 256, 256, 0, stream>>>(hist);
    k_hist<<<(Ee + 255) / 256, 256, 0, stream>>>(edges, batch, hist, ebuf);
    k_scan<<<1, 256, 0, stream>>>(hist, offsets, cursor);
    k_scatter<<<(Ee + 255) / 256, 256, 0, stream>>>(ebuf, cursor, order);
    k_pad<<<2048, 256, 0, stream>>>(x, x64);
    k_h<<<2048, 256, 0, stream>>>(x64, W, b, h, Nn);
    k_reduce<<<Gg, 256, 0, stream>>>(h, pos, attn, W_rbf, W_read, b_read,
                                     edges, order, offsets, hist, out);
}

// Round 11
// 363.981 us; speedup vs baseline: 2.7429x; 1.3975x over previous
//
#include <hip/hip_runtime.h>
#include <math.h>

constexpr int Nn = 200000, Ee = 400000, Gg = 4096;

__device__ __forceinline__ float elu1(float v) {
    return v > 0.f ? v : __expf(v) - 1.f;
}

// ----------------------------------------------------------- zero hist ----
__global__ __launch_bounds__(256) void k_zero(int* __restrict__ hist) {
    int i = blockIdx.x * 256 + threadIdx.x;
    if (i < Gg) hist[i] = 0;
}

// ------------------------------------------- histogram + eb cache ---------
__global__ __launch_bounds__(256) void k_hist(const int* __restrict__ edges,
                                              const int* __restrict__ batch,
                                              int* __restrict__ hist,
                                              int* __restrict__ ebuf) {
    int e = blockIdx.x * 256 + threadIdx.x;
    if (e >= Ee) return;
    int eb = batch[edges[2 * e]];
    ebuf[e] = eb;
    atomicAdd(&hist[eb], 1);
}

// ------------------- exclusive scan (1 block, 256 thr, 16 bins/thread) ----
__global__ __launch_bounds__(256) void k_scan(const int* __restrict__ hist,
                                              int* __restrict__ offsets,
                                              int* __restrict__ cursor) {
    __shared__ int part[256];
    int t = threadIdx.x;
    int local[16];
    int s = 0;
#pragma unroll
    for (int j = 0; j < 16; ++j) { local[j] = s; s += hist[t * 16 + j]; }
    part[t] = s;
    __syncthreads();
    for (int off = 1; off < 256; off <<= 1) {
        int v = (t >= off) ? part[t - off] : 0;
        __syncthreads();
        part[t] += v;
        __syncthreads();
    }
    int pre = (t == 0) ? 0 : part[t - 1];
#pragma unroll
    for (int j = 0; j < 16; ++j) {
        int o = pre + local[j];
        offsets[t * 16 + j] = o;
        cursor[t * 16 + j]  = o;
    }
}

// ------------------------------------------------------------ scatter -----
__global__ __launch_bounds__(256) void k_scatter(const int* __restrict__ ebuf,
                                                 int* __restrict__ cursor,
                                                 int* __restrict__ order) {
    int e = blockIdx.x * 256 + threadIdx.x;
    if (e >= Ee) return;
    int p = atomicAdd(&cursor[ebuf[e]], 1);
    order[p] = e;
}

// --------------------------------- pad x (N x 63) -> x64 (N x 64, 16B rows)
__global__ __launch_bounds__(256) void k_pad(const float* __restrict__ x,
                                             float* __restrict__ x64) {
    int total = Nn * 64;
    for (int i = blockIdx.x * 256 + threadIdx.x; i < total; i += gridDim.x * 256) {
        int n = i >> 6, k = i & 63;
        x64[i] = (k < 63) ? x[n * 63 + k] : 0.f;
    }
}

// ------------------------------------------------------- h = x @ W + b ----
// Register-tiled LDS GEMM: block tile 128 nodes x 128 dims, K=64 (padded),
// thread tile 8x8. LDS quad layouts (for node/dim idx, K-quad kq):
//   f4pos = kq*128 + ((p + kq) & 127),  p = (idx&7)*16 + (idx>>3)
// -> a-frag read banks 4(tm+kq)%32 (4 distinct/wave), b-frag 4(tn+kq)%32
//    (2-way = free), everything 16B-aligned. W staged once per block.
__global__ __launch_bounds__(256, 2) void k_h(const float4* __restrict__ x64q,
                                              const float* __restrict__ W,
                                              const float* __restrict__ b,
                                              float* __restrict__ h, int N) {
    __shared__ float4 xs[2048];   // 32 KB
    __shared__ float4 ws[2048];   // 32 KB
    int t  = threadIdx.x;
    int tn = t & 15;              // dim-group: dims d = tn*8 + i
    int tm = t >> 4;              // node-group: nodes n = tm*8 + j

    // ---- stage W once (transpose scatter, amortized over tiles) ----
    {
        float* wsf = (float*)ws;
        for (int i = t; i < 8192; i += 256) {     // i = k*128 + d
            int k = i >> 7, d = i & 127;
            float v  = (k < 63) ? W[k * 128 + d] : 0.f;
            int  pd  = ((d & 7) << 4) | (d >> 3);
            int  kq  = k >> 2, ki = k & 3;
            wsf[(((kq << 7) + ((pd + kq) & 127)) << 2) + ki] = v;
        }
    }
    float bd[8];
#pragma unroll
    for (int i = 0; i < 8; ++i) bd[i] = b[tn * 8 + i];

    int ntiles = (N + 127) >> 7;
    for (int tile = blockIdx.x; tile < ntiles; tile += gridDim.x) {
        int base = tile << 7;
        __syncthreads();   // xs readers of previous tile done (also fences W stage)
        // ---- stage x tile: 2048 quads, 8 per thread, coalesced f4 reads ----
#pragma unroll
        for (int s = 0; s < 8; ++s) {
            int q  = t + s * 256;
            int n  = q >> 4, kq = q & 15;
            int nn = base + n; if (nn > N - 1) nn = N - 1;
            int pn = ((n & 7) << 4) | (n >> 3);
            xs[(kq << 7) + ((pn + kq) & 127)] = x64q[(size_t)nn * 16 + kq];
        }
        __syncthreads();

        float acc[8][8];
#pragma unroll
        for (int j = 0; j < 8; ++j)
#pragma unroll
            for (int i = 0; i < 8; ++i) acc[j][i] = bd[i];

#pragma unroll 2
        for (int kq = 0; kq < 16; ++kq) {
            float4 af[8], bf[8];
#pragma unroll
            for (int j = 0; j < 8; ++j)
                af[j] = xs[(kq << 7) + (((j << 4) + tm + kq) & 127)];
#pragma unroll
            for (int i = 0; i < 8; ++i)
                bf[i] = ws[(kq << 7) + (((i << 4) + tn + kq) & 127)];
#pragma unroll
            for (int j = 0; j < 8; ++j)
#pragma unroll
                for (int i = 0; i < 8; ++i) {
                    acc[j][i] = fmaf(af[j].x, bf[i].x, acc[j][i]);
                    acc[j][i] = fmaf(af[j].y, bf[i].y, acc[j][i]);
                    acc[j][i] = fmaf(af[j].z, bf[i].z, acc[j][i]);
                    acc[j][i] = fmaf(af[j].w, bf[i].w, acc[j][i]);
                }
        }

        // ---- write h: 2 float4 per node row, coalesced across tn ----
#pragma unroll
        for (int j = 0; j < 8; ++j) {
            int n = base + tm * 8 + j;
            if (n < N) {
                float4 o0 = {acc[j][0], acc[j][1], acc[j][2], acc[j][3]};
                float4 o1 = {acc[j][4], acc[j][5], acc[j][6], acc[j][7]};
                float4* dst = (float4*)(h + (size_t)n * 128 + tn * 8);
                dst[0] = o0;
                dst[1] = o1;
            }
        }
    }
}

// --------------------------- per-segment reduction (no float atomics) -----
__global__ __launch_bounds__(256) void k_reduce(
    const float* __restrict__ h, const float* __restrict__ pos,
    const float* __restrict__ attn, const float* __restrict__ W_rbf,
    const float* __restrict__ W_read, const float* __restrict__ b_read,
    const int* __restrict__ edges, const int* __restrict__ order,
    const int* __restrict__ offsets, const int* __restrict__ hist,
    float* __restrict__ out) {

    __shared__ float lsum[4][256];
    __shared__ float lmax[4][256];

    int g    = blockIdx.x;
    int t    = threadIdx.x;
    int lane = t & 63;
    int wv   = t >> 6;
    int start = offsets[g];
    int cnt   = hist[g];

    const float2* Wr = (const float2*)W_rbf;
    float2 w0 = Wr[0 * 64 + lane];
    float2 w1 = Wr[1 * 64 + lane];
    float2 w2 = Wr[2 * 64 + lane];
    float2 w3 = Wr[3 * 64 + lane];
    float2 w4 = Wr[4 * 64 + lane];
    float2 w5 = Wr[5 * 64 + lane];
    float2 at = ((const float2*)attn)[lane];
    float2 wr = ((const float2*)W_read)[lane];
    float  br = b_read[0];

    float sx = 0.f, sy = 0.f;
    float mx = -INFINITY, my = -INFINITY;

    for (int i = wv; i < cnt; i += 4) {
        int e   = order[start + i];
        int src = edges[2 * e];
        int dst = edges[2 * e + 1];

        float dx = pos[dst * 3 + 0] - pos[src * 3 + 0];
        float dy = pos[dst * 3 + 1] - pos[src * 3 + 1];
        float dz = pos[dst * 3 + 2] - pos[src * 3 + 2];
        float dist = fmaxf(sqrtf(dx * dx + dy * dy + dz * dz), 0.1f);
        float r0 = __expf(-0.5f * (dist - 0.f) * (dist - 0.f));
        float r1 = __expf(-0.5f * (dist - 1.f) * (dist - 1.f));
        float r2 = __expf(-0.5f * (dist - 2.f) * (dist - 2.f));
        float r3 = __expf(-0.5f * (dist - 3.f) * (dist - 3.f));
        float r4 = __expf(-0.5f * (dist - 4.f) * (dist - 4.f));
        float r5 = __expf(-0.5f * (dist - 5.f) * (dist - 5.f));

        float2 hs = ((const float2*)(h + (size_t)src * 128))[lane];
        float2 hd = ((const float2*)(h + (size_t)dst * 128))[lane];
        float hex = elu1(hs.x + hd.x);
        float hey = elu1(hs.y + hd.y);

        float gx = r0 * w0.x + r1 * w1.x + r2 * w2.x + r3 * w3.x + r4 * w4.x + r5 * w5.x;
        float gy = r0 * w0.y + r1 * w1.y + r2 * w2.y + r3 * w3.y + r4 * w4.y + r5 * w5.y;

        float ax = elu1(hex * gx * at.x);
        float ay = elu1(hey * gy * at.y);

        float p = ax * wr.x + ay * wr.y;
#pragma unroll
        for (int off = 32; off; off >>= 1) p += __shfl_xor(p, off);
        float score = 1.f / (1.f + __expf(-(p + br)));

        sx = fmaf(ax, score, sx);
        sy = fmaf(ay, score, sy);
        mx = fmaxf(mx, ax);
        my = fmaxf(my, ay);
    }

    lsum[wv][lane * 2 + 0] = sx;
    lsum[wv][lane * 2 + 1] = sy;
    lmax[wv][lane * 2 + 0] = mx;
    lmax[wv][lane * 2 + 1] = my;
    __syncthreads();

    float r;
    if (t < 128) {
        r = lsum[0][t] + lsum[1][t] + lsum[2][t] + lsum[3][t];
    } else {
        int d = t - 128;
        float m = fmaxf(fmaxf(lmax[0][d], lmax[1][d]),
                        fmaxf(lmax[2][d], lmax[3][d]));
        r = (m > -3.0e38f) ? m : 0.f;   // empty segment -> 0 (isfinite fixup)
    }
    out[g * 256 + t] = r;
}

// ---------------------------------------------------------------- host ---
extern "C" void kernel_launch(void* const* d_in, const int* in_sizes, int n_in,
                              void* d_out, int out_size, void* d_ws, size_t ws_size,
                              hipStream_t stream) {
    const float* x      = (const float*)d_in[0];
    const float* pos    = (const float*)d_in[1];
    const float* W      = (const float*)d_in[2];
    const float* b      = (const float*)d_in[3];
    const float* attn   = (const float*)d_in[4];
    const float* W_rbf  = (const float*)d_in[5];
    const float* W_read = (const float*)d_in[6];
    const float* b_read = (const float*)d_in[7];
    const int*   edges  = (const int*)d_in[8];
    const int*   batch  = (const int*)d_in[9];
    float* out = (float*)d_out;

    char* p = (char*)d_ws;
    float* h       = (float*)p;                 p += (size_t)Nn * 128 * 4;  // 102.4 MB
    float* x64     = (float*)p;                 p += (size_t)Nn * 64 * 4;   //  51.2 MB
    int*   hist    = (int*)p;                   p += Gg * 4;
    int*   offsets = (int*)p;                   p += Gg * 4;
    int*   cursor  = (int*)p;                   p += Gg * 4;
    int*   ebuf    = (int*)p;                   p += Ee * 4;
    int*   order   = (int*)p;                   p += Ee * 4;

    k_zero<<<(Gg + 255) / 256, 256, 0, stream>>>(hist);
    k_hist<<<(Ee + 255) / 256, 256, 0, stream>>>(edges, batch, hist, ebuf);
    k_scan<<<1, 256, 0, stream>>>(hist, offsets, cursor);
    k_scatter<<<(Ee + 255) / 256, 256, 0, stream>>>(ebuf, cursor, order);
    k_pad<<<2048, 256, 0, stream>>>(x, x64);
    k_h<<<512, 256, 0, stream>>>((const float4*)x64, W, b, h, Nn);
    k_reduce<<<Gg, 256, 0, stream>>>(h, pos, attn, W_rbf, W_read, b_read,
                                     edges, order, offsets, hist, out);
}